// Round 11
// baseline (87.665 us; speedup 1.0000x reference)
//
#include <hip/hip_runtime.h>
#include <math.h>

#define A_CUBIC (-0.75f)
#define NB 2
#define NC 3
#define HH 144
#define NPB 2304      // patches per batch (48*48)
#define GG 14460      // real database patches per batch
#define GGP 14464     // padded to 113 tiles of 128 (pad rows are zeros)
#define DD 27
#define DP 28         // row stride; [27] = gn (gf) or -1 (m)
#define NGT 113       // g-tiles of 128
#define NSPLIT 16     // g-splits per n-tile
#define APAD 68       // k-major A stride (16B-aligned rows, low conflict)
#define BPAD 132      // k-major B stride

__constant__ int c_seg_start[15] = {0,2209,2738,2859,5068,5597,5718,7927,8456,8577,10786,11315,11436,13740,14316};
__constant__ int c_seg_gw[15]    = {47,23,11, 47,23,11, 47,23,11, 47,23,11, 48,24,12};
__constant__ int c_seg_oy[15]    = {1,1,1, 1,1,1, 2,2,2, 2,2,2, 0,0,0};
__constant__ int c_seg_ox[15]    = {1,1,1, 2,2,2, 1,1,1, 2,2,2, 0,0,0};
__constant__ int c_seg_src[15]   = {0,1,2, 0,1,2, 0,1,2, 0,1,2, 0,1,2};

__device__ __forceinline__ float cubicw(float t) {
    float at = fabsf(t);
    if (at <= 1.0f) return ((A_CUBIC + 2.0f) * at - (A_CUBIC + 3.0f)) * at * at + 1.0f;
    if (at < 2.0f)  return A_CUBIC * (((at - 5.0f) * at + 8.0f) * at - 4.0f);
    return 0.0f;
}

// K1: bicubic downscale tar -> s1 (72x72), s2 (36x36), PLUS m-row build + best init.
__global__ void prep_k(const float* __restrict__ tar, const float* __restrict__ inp,
                       float* __restrict__ s1, float* __restrict__ s2,
                       float* __restrict__ m, unsigned long long* __restrict__ best) {
    int t = blockIdx.x * 256 + threadIdx.x;
    const int total1 = NB * NC * 72 * 72;
    const int total2 = NB * NC * 36 * 36;
    if (t < total1 + total2) {
        float* dst; int O; int idx;
        if (t < total1) { dst = s1; O = 72; idx = t; }
        else            { dst = s2; O = 36; idx = t - total1; }
        int x  = idx % O;
        int y  = (idx / O) % O;
        int bc = idx / (O * O);
        const float* src = tar + (size_t)bc * HH * HH;
        float scale = (float)(143.0 / (double)(O - 1));
        float fy = (float)y * scale;
        float iyf = floorf(fy); float fry = fy - iyf; int iy = (int)iyf;
        float fx = (float)x * scale;
        float ixf = floorf(fx); float frx = fx - ixf; int ix = (int)ixf;
        float wy[4], wx[4];
        #pragma unroll
        for (int d = 0; d < 4; ++d) {
            wy[d] = cubicw(fry - (float)(d - 1));
            wx[d] = cubicw(frx - (float)(d - 1));
        }
        float acc = 0.0f;
        #pragma unroll
        for (int dx = 0; dx < 4; ++dx) {
            int cx = min(max(ix - 1 + dx, 0), HH - 1);
            float inner = 0.0f;
            #pragma unroll
            for (int dy = 0; dy < 4; ++dy) {
                int cy = min(max(iy - 1 + dy, 0), HH - 1);
                inner += wy[dy] * src[cy * HH + cx];
            }
            acc += wx[dx] * inner;
        }
        dst[idx] = acc;
    } else {
        int u = t - (total1 + total2);
        if (u >= NB * NPB) return;
        int b = u / NPB, n = u % NPB;
        int hc = n / 48, wc = n % 48;
        const float* ib = inp + (size_t)b * NC * HH * HH;
        const float* tb = tar + (size_t)b * NC * HH * HH;
        float* row = m + (size_t)u * DP;
        #pragma unroll
        for (int c = 0; c < 3; ++c)
            #pragma unroll
            for (int dy = 0; dy < 3; ++dy)
                #pragma unroll
                for (int dx = 0; dx < 3; ++dx) {
                    int off = (c * HH + hc * 3 + dy) * HH + wc * 3 + dx;
                    row[(c * 3 + dy) * 3 + dx] = ib[off] + tb[off];
                }
        row[27] = -1.0f;
        best[u] = 0ULL;
    }
}

// K2: build gf database rows [B*GGP][28]; row[27] = |g|^2; pad rows (g>=GG) zeroed.
__global__ void build_gf_k(const float* __restrict__ tar, const float* __restrict__ s1,
                           const float* __restrict__ s2, float* __restrict__ gf) {
    int t = blockIdx.x * 256 + threadIdx.x;
    if (t >= NB * GGP) return;
    int b = t / GGP, g = t % GGP;
    float* row = gf + (size_t)t * DP;
    if (g >= GG) {
        #pragma unroll
        for (int i = 0; i < DP; ++i) row[i] = 0.0f;
        return;
    }
    int s = 0;
    #pragma unroll
    for (int k = 1; k < 15; ++k) if (g >= c_seg_start[k]) s = k;
    int p  = g - c_seg_start[s];
    int gw = c_seg_gw[s];
    int hc = p / gw, wc = p % gw;
    int oy = c_seg_oy[s], ox = c_seg_ox[s];
    int srci = c_seg_src[s];
    const float* img; int sz;
    if (srci == 0)      { img = tar; sz = 144; }
    else if (srci == 1) { img = s1;  sz = 72;  }
    else                { img = s2;  sz = 36;  }
    const float* base = img + (size_t)b * NC * sz * sz;
    int y0 = oy + hc * 3, x0 = ox + wc * 3;
    float acc = 0.0f;
    #pragma unroll
    for (int c = 0; c < 3; ++c)
        #pragma unroll
        for (int dy = 0; dy < 3; ++dy)
            #pragma unroll
            for (int dx = 0; dx < 3; ++dx) {
                float v = base[((size_t)c * sz + y0 + dy) * sz + x0 + dx];
                row[(c * 3 + dy) * 3 + dx] = v;
                acc = fmaf(v, v, acc);
            }
    row[27] = acc;
}

// K4: register-tiled GEMM + fused argmax. Block = 64n x (NGT/NSPLIT g-tiles of 128).
// 256 threads as 16(tx:n) x 16(ty:g); each thread: acc[4n][8g] in registers
// (accumulator is written every k-step -> cannot be demoted). Operands staged
// k-major in LDS; 3x ds_read_b128 per k-step feeds 32 FMAs.
__global__ __launch_bounds__(256) void argmin_k(
        const float* __restrict__ gf, const float* __restrict__ m,
        unsigned long long* __restrict__ best) {
    __shared__ __align__(16) float Al[28 * APAD];    // 7.4 KB
    __shared__ __align__(16) float Bl[28 * BPAD];    // 14.4 KB
    __shared__ float rv[64 * 17];                    // padded: conflict-free reduce
    __shared__ int   ri[64 * 17];
    int tid = threadIdx.x;
    int tx = tid & 15;           // n-subtile
    int ty = tid >> 4;           // g-subtile
    int nt = blockIdx.y;         // 0..71
    int n0 = nt * 64;
    int b  = nt / 36;
    int s  = blockIdx.x;         // 0..15
    int t0 = (s * NGT) >> 4;
    int t1 = ((s + 1) * NGT) >> 4;

    // stage A once (transpose to k-major); coalesced global reads
    {
        const float* src = m + (size_t)n0 * DP;
        for (int idx = tid; idx < 64 * DP; idx += 256) {
            int r = idx / DP, k = idx - r * DP;
            Al[k * APAD + r] = src[idx];
        }
    }

    float bv[4]; int bi[4];
    #pragma unroll
    for (int i = 0; i < 4; ++i) { bv[i] = -3.0e38f; bi[i] = 0; }

    const float* gbase = gf + (size_t)b * GGP * DP;
    for (int t = t0; t < t1; ++t) {
        __syncthreads();
        {   // stage B tile (128 g-rows, transpose to k-major)
            const float* src = gbase + (size_t)t * 128 * DP;
            for (int idx = tid; idx < 128 * DP; idx += 256) {
                int r = idx / DP, k = idx - r * DP;
                Bl[k * BPAD + r] = src[idx];
            }
        }
        __syncthreads();

        float acc[4][8];
        #pragma unroll
        for (int i = 0; i < 4; ++i)
            #pragma unroll
            for (int j = 0; j < 8; ++j) acc[i][j] = 0.0f;

        #pragma unroll
        for (int k = 0; k < 28; ++k) {
            float4 a  = *(const float4*)&Al[k * APAD + tx * 4];
            float4 p  = *(const float4*)&Bl[k * BPAD + ty * 8];
            float4 q  = *(const float4*)&Bl[k * BPAD + ty * 8 + 4];
            float av[4] = {a.x, a.y, a.z, a.w};
            float gv[8] = {p.x, p.y, p.z, p.w, q.x, q.y, q.z, q.w};
            #pragma unroll
            for (int i = 0; i < 4; ++i)
                #pragma unroll
                for (int j = 0; j < 8; ++j)
                    acc[i][j] = fmaf(av[i], gv[j], acc[i][j]);
        }

        int gg0 = t * 128 + ty * 8;
        #pragma unroll
        for (int j = 0; j < 8; ++j) {       // j ascending + t ascending:
            #pragma unroll
            for (int i = 0; i < 4; ++i) {   // strict > keeps first (smallest g) max
                if (acc[i][j] > bv[i]) { bv[i] = acc[i][j]; bi[i] = gg0 + j; }
            }
        }
    }

    #pragma unroll
    for (int i = 0; i < 4; ++i) {
        rv[(tx * 4 + i) * 17 + ty] = bv[i];
        ri[(tx * 4 + i) * 17 + ty] = bi[i];
    }
    __syncthreads();
    if (tid < 64) {
        float v = -3.0e38f; int idx = 0x7fffffff;
        #pragma unroll
        for (int y = 0; y < 16; ++y) {
            float vv = rv[tid * 17 + y]; int ii = ri[tid * 17 + y];
            if (vv > v || (vv == v && ii < idx)) { v = vv; idx = ii; }
        }
        unsigned u = __float_as_uint(v);
        u ^= (unsigned)(((int)u >> 31)) | 0x80000000u;
        atomicMax(&best[n0 + tid], ((unsigned long long)u << 32) | (unsigned)(~idx));
    }
}

// K5: decode best, gather sel, fold to image, block-partial L1 sums
__global__ void finalize_k(const float* __restrict__ gf,
                           const unsigned long long* __restrict__ best,
                           const float* __restrict__ inp,
                           float* __restrict__ out, float* __restrict__ lpart) {
    __shared__ float red[256];
    int t = blockIdx.x * 256 + threadIdx.x;
    float lsum = 0.0f;
    if (t < NB * NPB) {
        int b = t / NPB, n = t % NPB;
        unsigned long long pk = best[t];
        int bi = (int)(~(unsigned)(pk & 0xFFFFFFFFull));
        int hc = n / 48, wc = n % 48;
        const float* grow = gf + ((size_t)b * GGP + bi) * DP;
        const float* ib   = inp + (size_t)b * NC * HH * HH;
        float* sel = out + 1 + (size_t)b * NC * HH * HH;
        #pragma unroll
        for (int c = 0; c < 3; ++c)
            #pragma unroll
            for (int dy = 0; dy < 3; ++dy)
                #pragma unroll
                for (int dx = 0; dx < 3; ++dx) {
                    int d = (c * 3 + dy) * 3 + dx;
                    float sv = grow[d];
                    int off = (c * HH + hc * 3 + dy) * HH + wc * 3 + dx;
                    sel[off] = sv;
                    lsum += fabsf(ib[off] - sv);
                }
    }
    red[threadIdx.x] = lsum;
    __syncthreads();
    for (int s = 128; s > 0; s >>= 1) {
        if (threadIdx.x < s) red[threadIdx.x] += red[threadIdx.x + s];
        __syncthreads();
    }
    if (threadIdx.x == 0) lpart[blockIdx.x] = red[0];
}

// K6: scalar loss mean
__global__ void sum_k(const float* __restrict__ lpart, float* __restrict__ out) {
    if (threadIdx.x == 0) {
        float s = 0.0f;
        for (int i = 0; i < 18; ++i) s += lpart[i];
        out[0] = s * (1.0f / 124416.0f);
    }
}

extern "C" void kernel_launch(void* const* d_in, const int* in_sizes, int n_in,
                              void* d_out, int out_size, void* d_ws, size_t ws_size,
                              hipStream_t stream) {
    const float* inp = (const float*)d_in[0];
    const float* tar = (const float*)d_in[1];
    float* out = (float*)d_out;
    float* ws  = (float*)d_ws;

    float* s1 = ws;                       // 31104
    float* s2 = s1 + 31104;               // 7776
    float* gf = s2 + 7776;                // 2*14464*28 = 809984
    float* m  = gf + 809984;              // 2*2304*28 = 129024
    unsigned long long* best = (unsigned long long*)(m + 129024);  // 4608 u64
    float* lp = (float*)(best + 4608);    // 18

    prep_k    <<<(43488 + 255) / 256, 256, 0, stream>>>(tar, inp, s1, s2, m, best);
    build_gf_k<<<(NB * GGP + 255) / 256, 256, 0, stream>>>(tar, s1, s2, gf);
    argmin_k  <<<dim3(NSPLIT, 72), 256, 0, stream>>>(gf, m, best);
    finalize_k<<<18, 256, 0, stream>>>(gf, best, inp, out, lp);
    sum_k     <<<1, 64, 0, stream>>>(lp, out);
}

// Round 12
// 80.018 us; speedup vs baseline: 1.0956x; 1.0956x over previous
//
#include <hip/hip_runtime.h>
#include <math.h>

#define A_CUBIC (-0.75f)
#define NB 2
#define NC 3
#define HH 144
#define NPB 2304      // patches per batch (48*48)
#define NTOT 4608     // NB*NPB
#define GG 14460      // real database patches per batch
#define GGP 14464     // padded to 113 tiles of 128 (pad rows zero)
#define GTOT 28928    // NB*GGP
#define DD 27
#define NGT 113       // g-tiles of 128
#define NSPLIT 16

__constant__ int c_seg_start[15] = {0,2209,2738,2859,5068,5597,5718,7927,8456,8577,10786,11315,11436,13740,14316};
__constant__ int c_seg_gw[15]    = {47,23,11, 47,23,11, 47,23,11, 47,23,11, 48,24,12};
__constant__ int c_seg_oy[15]    = {1,1,1, 1,1,1, 2,2,2, 2,2,2, 0,0,0};
__constant__ int c_seg_ox[15]    = {1,1,1, 2,2,2, 1,1,1, 2,2,2, 0,0,0};
__constant__ int c_seg_src[15]   = {0,1,2, 0,1,2, 0,1,2, 0,1,2, 0,1,2};

__device__ __forceinline__ float cubicw(float t) {
    float at = fabsf(t);
    if (at <= 1.0f) return ((A_CUBIC + 2.0f) * at - (A_CUBIC + 3.0f)) * at * at + 1.0f;
    if (at < 2.0f)  return A_CUBIC * (((at - 5.0f) * at + 8.0f) * at - 4.0f);
    return 0.0f;
}

// K1: bicubic downscale tar -> s1, s2; build mT (k-major) rows; init best.
__global__ void prep_k(const float* __restrict__ tar, const float* __restrict__ inp,
                       float* __restrict__ s1, float* __restrict__ s2,
                       float* __restrict__ mT, unsigned long long* __restrict__ best) {
    int t = blockIdx.x * 256 + threadIdx.x;
    const int total1 = NB * NC * 72 * 72;
    const int total2 = NB * NC * 36 * 36;
    if (t < total1 + total2) {
        float* dst; int O; int idx;
        if (t < total1) { dst = s1; O = 72; idx = t; }
        else            { dst = s2; O = 36; idx = t - total1; }
        int x  = idx % O;
        int y  = (idx / O) % O;
        int bc = idx / (O * O);
        const float* src = tar + (size_t)bc * HH * HH;
        float scale = (float)(143.0 / (double)(O - 1));
        float fy = (float)y * scale;
        float iyf = floorf(fy); float fry = fy - iyf; int iy = (int)iyf;
        float fx = (float)x * scale;
        float ixf = floorf(fx); float frx = fx - ixf; int ix = (int)ixf;
        float wy[4], wx[4];
        #pragma unroll
        for (int d = 0; d < 4; ++d) {
            wy[d] = cubicw(fry - (float)(d - 1));
            wx[d] = cubicw(frx - (float)(d - 1));
        }
        float acc = 0.0f;
        #pragma unroll
        for (int dx = 0; dx < 4; ++dx) {
            int cx = min(max(ix - 1 + dx, 0), HH - 1);
            float inner = 0.0f;
            #pragma unroll
            for (int dy = 0; dy < 4; ++dy) {
                int cy = min(max(iy - 1 + dy, 0), HH - 1);
                inner += wy[dy] * src[cy * HH + cx];
            }
            acc += wx[dx] * inner;
        }
        dst[idx] = acc;
    } else {
        int u = t - (total1 + total2);
        if (u >= NTOT) return;
        int b = u / NPB, n = u % NPB;
        int hc = n / 48, wc = n % 48;
        const float* ib = inp + (size_t)b * NC * HH * HH;
        const float* tb = tar + (size_t)b * NC * HH * HH;
        #pragma unroll
        for (int c = 0; c < 3; ++c)
            #pragma unroll
            for (int dy = 0; dy < 3; ++dy)
                #pragma unroll
                for (int dx = 0; dx < 3; ++dx) {
                    int off = (c * HH + hc * 3 + dy) * HH + wc * 3 + dx;
                    int d   = (c * 3 + dy) * 3 + dx;
                    mT[d * NTOT + u] = ib[off] + tb[off];
                }
        mT[27 * NTOT + u] = -1.0f;
        best[u] = 0ULL;
    }
}

// K2: build gfT (k-major) [28][GTOT]; plane 27 = |g|^2; pad g>=GG zeroed.
__global__ void build_gf_k(const float* __restrict__ tar, const float* __restrict__ s1,
                           const float* __restrict__ s2, float* __restrict__ gfT) {
    int t = blockIdx.x * 256 + threadIdx.x;
    if (t >= GTOT) return;
    int b = t / GGP, g = t % GGP;
    if (g >= GG) {
        #pragma unroll
        for (int d = 0; d < 28; ++d) gfT[d * GTOT + t] = 0.0f;
        return;
    }
    int s = 0;
    #pragma unroll
    for (int k = 1; k < 15; ++k) if (g >= c_seg_start[k]) s = k;
    int p  = g - c_seg_start[s];
    int gw = c_seg_gw[s];
    int hc = p / gw, wc = p % gw;
    int oy = c_seg_oy[s], ox = c_seg_ox[s];
    int srci = c_seg_src[s];
    const float* img; int sz;
    if (srci == 0)      { img = tar; sz = 144; }
    else if (srci == 1) { img = s1;  sz = 72;  }
    else                { img = s2;  sz = 36;  }
    const float* base = img + (size_t)b * NC * sz * sz;
    int y0 = oy + hc * 3, x0 = ox + wc * 3;
    float acc = 0.0f;
    #pragma unroll
    for (int c = 0; c < 3; ++c)
        #pragma unroll
        for (int dy = 0; dy < 3; ++dy)
            #pragma unroll
            for (int dx = 0; dx < 3; ++dx) {
                float v = base[((size_t)c * sz + y0 + dy) * sz + x0 + dx];
                gfT[((c * 3 + dy) * 3 + dx) * GTOT + t] = v;
                acc = fmaf(v, v, acc);
            }
    gfT[27 * GTOT + t] = acc;
}

#define DOT32_MUL(a, p, q)                                                     \
    acc[0][0]=(a).x*(p).x; acc[0][1]=(a).x*(p).y; acc[0][2]=(a).x*(p).z;       \
    acc[0][3]=(a).x*(p).w; acc[0][4]=(a).x*(q).x; acc[0][5]=(a).x*(q).y;       \
    acc[0][6]=(a).x*(q).z; acc[0][7]=(a).x*(q).w;                              \
    acc[1][0]=(a).y*(p).x; acc[1][1]=(a).y*(p).y; acc[1][2]=(a).y*(p).z;       \
    acc[1][3]=(a).y*(p).w; acc[1][4]=(a).y*(q).x; acc[1][5]=(a).y*(q).y;       \
    acc[1][6]=(a).y*(q).z; acc[1][7]=(a).y*(q).w;                              \
    acc[2][0]=(a).z*(p).x; acc[2][1]=(a).z*(p).y; acc[2][2]=(a).z*(p).z;       \
    acc[2][3]=(a).z*(p).w; acc[2][4]=(a).z*(q).x; acc[2][5]=(a).z*(q).y;       \
    acc[2][6]=(a).z*(q).z; acc[2][7]=(a).z*(q).w;                              \
    acc[3][0]=(a).w*(p).x; acc[3][1]=(a).w*(p).y; acc[3][2]=(a).w*(p).z;       \
    acc[3][3]=(a).w*(p).w; acc[3][4]=(a).w*(q).x; acc[3][5]=(a).w*(q).y;       \
    acc[3][6]=(a).w*(q).z; acc[3][7]=(a).w*(q).w;

#define DOT32_FMA(a, p, q)                                                     \
    acc[0][0]=fmaf((a).x,(p).x,acc[0][0]); acc[0][1]=fmaf((a).x,(p).y,acc[0][1]); \
    acc[0][2]=fmaf((a).x,(p).z,acc[0][2]); acc[0][3]=fmaf((a).x,(p).w,acc[0][3]); \
    acc[0][4]=fmaf((a).x,(q).x,acc[0][4]); acc[0][5]=fmaf((a).x,(q).y,acc[0][5]); \
    acc[0][6]=fmaf((a).x,(q).z,acc[0][6]); acc[0][7]=fmaf((a).x,(q).w,acc[0][7]); \
    acc[1][0]=fmaf((a).y,(p).x,acc[1][0]); acc[1][1]=fmaf((a).y,(p).y,acc[1][1]); \
    acc[1][2]=fmaf((a).y,(p).z,acc[1][2]); acc[1][3]=fmaf((a).y,(p).w,acc[1][3]); \
    acc[1][4]=fmaf((a).y,(q).x,acc[1][4]); acc[1][5]=fmaf((a).y,(q).y,acc[1][5]); \
    acc[1][6]=fmaf((a).y,(q).z,acc[1][6]); acc[1][7]=fmaf((a).y,(q).w,acc[1][7]); \
    acc[2][0]=fmaf((a).z,(p).x,acc[2][0]); acc[2][1]=fmaf((a).z,(p).y,acc[2][1]); \
    acc[2][2]=fmaf((a).z,(p).z,acc[2][2]); acc[2][3]=fmaf((a).z,(p).w,acc[2][3]); \
    acc[2][4]=fmaf((a).z,(q).x,acc[2][4]); acc[2][5]=fmaf((a).z,(q).y,acc[2][5]); \
    acc[2][6]=fmaf((a).z,(q).z,acc[2][6]); acc[2][7]=fmaf((a).z,(q).w,acc[2][7]); \
    acc[3][0]=fmaf((a).w,(p).x,acc[3][0]); acc[3][1]=fmaf((a).w,(p).y,acc[3][1]); \
    acc[3][2]=fmaf((a).w,(p).z,acc[3][2]); acc[3][3]=fmaf((a).w,(p).w,acc[3][3]); \
    acc[3][4]=fmaf((a).w,(q).x,acc[3][4]); acc[3][5]=fmaf((a).w,(q).y,acc[3][5]); \
    acc[3][6]=fmaf((a).w,(q).z,acc[3][6]); acc[3][7]=fmaf((a).w,(q).w,acc[3][7]);

// K4: register-tiled GEMM + fused argmax on PRE-TRANSPOSED operands.
// Staging = pure float4 copies (no div/transpose, conflict-free).
// k-loop reads: A 2-way (free), B 4-addr broadcast (free). 32 FMA / k-step.
__global__ __launch_bounds__(256) void argmin_k(
        const float* __restrict__ gfT, const float* __restrict__ mT,
        unsigned long long* __restrict__ best) {
    __shared__ __align__(16) float Al[28 * 64];      // 7 KB
    __shared__ __align__(16) float Bl[28 * 128];     // 14 KB
    __shared__ float rv[64 * 17];
    __shared__ int   ri[64 * 17];
    int tid = threadIdx.x;
    int tx = tid & 15;           // n-subtile (4 n each)
    int ty = tid >> 4;           // g-subtile (8 g each)
    int nt = blockIdx.y;         // 0..71
    int n0 = nt * 64;
    int b  = nt / 36;
    int s  = blockIdx.x;         // 0..15
    int t0 = (s * NGT) >> 4;
    int t1 = ((s + 1) * NGT) >> 4;

    // stage A once: 28 k-planes x 64 n = 448 float4
    for (int idx = tid; idx < 448; idx += 256) {
        int k = idx >> 4, x = idx & 15;
        *(float4*)&Al[k * 64 + x * 4] = *(const float4*)&mT[k * NTOT + n0 + x * 4];
    }

    float bv[4]; int bi[4];
    #pragma unroll
    for (int i = 0; i < 4; ++i) { bv[i] = -3.0e38f; bi[i] = 0; }

    const float* gb = gfT + b * GGP;
    for (int t = t0; t < t1; ++t) {
        __syncthreads();
        // stage B tile: 28 k-planes x 128 g = 896 float4
        for (int idx = tid; idx < 896; idx += 256) {
            int k = idx >> 5, x = idx & 31;
            *(float4*)&Bl[k * 128 + x * 4] = *(const float4*)&gb[k * GTOT + t * 128 + x * 4];
        }
        __syncthreads();

        float acc[4][8];
        {
            float4 a = *(const float4*)&Al[tx * 4];
            float4 p = *(const float4*)&Bl[ty * 8];
            float4 q = *(const float4*)&Bl[ty * 8 + 4];
            DOT32_MUL(a, p, q)
        }
        #pragma unroll
        for (int k = 1; k < 28; ++k) {
            float4 a = *(const float4*)&Al[k * 64 + tx * 4];
            float4 p = *(const float4*)&Bl[k * 128 + ty * 8];
            float4 q = *(const float4*)&Bl[k * 128 + ty * 8 + 4];
            DOT32_FMA(a, p, q)
        }

        int gg0 = t * 128 + ty * 8;
        #pragma unroll
        for (int j = 0; j < 8; ++j) {       // t,j ascending: strict > keeps first max
            #pragma unroll
            for (int i = 0; i < 4; ++i) {
                if (acc[i][j] > bv[i]) { bv[i] = acc[i][j]; bi[i] = gg0 + j; }
            }
        }
    }

    #pragma unroll
    for (int i = 0; i < 4; ++i) {
        rv[(tx * 4 + i) * 17 + ty] = bv[i];
        ri[(tx * 4 + i) * 17 + ty] = bi[i];
    }
    __syncthreads();
    if (tid < 64) {
        float v = -3.0e38f; int idx = 0x7fffffff;
        #pragma unroll
        for (int y = 0; y < 16; ++y) {
            float vv = rv[tid * 17 + y]; int ii = ri[tid * 17 + y];
            if (vv > v || (vv == v && ii < idx)) { v = vv; idx = ii; }
        }
        unsigned u = __float_as_uint(v);
        u ^= (unsigned)(((int)u >> 31)) | 0x80000000u;
        atomicMax(&best[n0 + tid], ((unsigned long long)u << 32) | (unsigned)(~idx));
    }
}

// K5: decode best, gather sel (strided from gfT), fold, block-partial L1 sums
__global__ void finalize_k(const float* __restrict__ gfT,
                           const unsigned long long* __restrict__ best,
                           const float* __restrict__ inp,
                           float* __restrict__ out, float* __restrict__ lpart) {
    __shared__ float red[256];
    int t = blockIdx.x * 256 + threadIdx.x;
    float lsum = 0.0f;
    if (t < NTOT) {
        int b = t / NPB, n = t % NPB;
        unsigned long long pk = best[t];
        int bi = (int)(~(unsigned)(pk & 0xFFFFFFFFull));
        int hc = n / 48, wc = n % 48;
        const float* ib = inp + (size_t)b * NC * HH * HH;
        float* sel = out + 1 + (size_t)b * NC * HH * HH;
        #pragma unroll
        for (int c = 0; c < 3; ++c)
            #pragma unroll
            for (int dy = 0; dy < 3; ++dy)
                #pragma unroll
                for (int dx = 0; dx < 3; ++dx) {
                    int d = (c * 3 + dy) * 3 + dx;
                    float sv = gfT[(size_t)d * GTOT + b * GGP + bi];
                    int off = (c * HH + hc * 3 + dy) * HH + wc * 3 + dx;
                    sel[off] = sv;
                    lsum += fabsf(ib[off] - sv);
                }
    }
    red[threadIdx.x] = lsum;
    __syncthreads();
    for (int s = 128; s > 0; s >>= 1) {
        if (threadIdx.x < s) red[threadIdx.x] += red[threadIdx.x + s];
        __syncthreads();
    }
    if (threadIdx.x == 0) lpart[blockIdx.x] = red[0];
}

// K6: scalar loss mean
__global__ void sum_k(const float* __restrict__ lpart, float* __restrict__ out) {
    if (threadIdx.x == 0) {
        float s = 0.0f;
        for (int i = 0; i < 18; ++i) s += lpart[i];
        out[0] = s * (1.0f / 124416.0f);
    }
}

extern "C" void kernel_launch(void* const* d_in, const int* in_sizes, int n_in,
                              void* d_out, int out_size, void* d_ws, size_t ws_size,
                              hipStream_t stream) {
    const float* inp = (const float*)d_in[0];
    const float* tar = (const float*)d_in[1];
    float* out = (float*)d_out;
    float* ws  = (float*)d_ws;

    float* s1  = ws;                        // 31104
    float* s2  = s1 + 31104;                // 7776
    float* gfT = s2 + 7776;                 // 28*28928 = 809984
    float* mT  = gfT + 809984;              // 28*4608  = 129024
    unsigned long long* best = (unsigned long long*)(mT + 129024);  // 4608 u64
    float* lp  = (float*)(best + 4608);     // 18

    prep_k    <<<(43488 + 255) / 256, 256, 0, stream>>>(tar, inp, s1, s2, mT, best);
    build_gf_k<<<(GTOT + 255) / 256, 256, 0, stream>>>(tar, s1, s2, gfT);
    argmin_k  <<<dim3(NSPLIT, 72), 256, 0, stream>>>(gfT, mT, best);
    finalize_k<<<18, 256, 0, stream>>>(gfT, best, inp, out, lp);
    sum_k     <<<1, 64, 0, stream>>>(lp, out);
}

// Round 13
// 74.805 us; speedup vs baseline: 1.1719x; 1.0697x over previous
//
#include <hip/hip_runtime.h>
#include <math.h>

#define A_CUBIC (-0.75f)
#define NB 2
#define NC 3
#define HH 144
#define NPB 2304      // patches per batch (48*48)
#define NTOT 4608     // NB*NPB
#define GG 14460      // real database patches per batch
#define GGP 14464     // padded to 113 tiles of 128 (pad rows zero)
#define GTOT 28928    // NB*GGP
#define NGT 113       // g-tiles of 128
#define NSPLIT 28

__constant__ int c_seg_start[15] = {0,2209,2738,2859,5068,5597,5718,7927,8456,8577,10786,11315,11436,13740,14316};
__constant__ int c_seg_gw[15]    = {47,23,11, 47,23,11, 47,23,11, 47,23,11, 48,24,12};
__constant__ int c_seg_oy[15]    = {1,1,1, 1,1,1, 2,2,2, 2,2,2, 0,0,0};
__constant__ int c_seg_ox[15]    = {1,1,1, 2,2,2, 1,1,1, 2,2,2, 0,0,0};
__constant__ int c_seg_src[15]   = {0,1,2, 0,1,2, 0,1,2, 0,1,2, 0,1,2};

__device__ __forceinline__ float cubicw(float t) {
    float at = fabsf(t);
    if (at <= 1.0f) return ((A_CUBIC + 2.0f) * at - (A_CUBIC + 3.0f)) * at * at + 1.0f;
    if (at < 2.0f)  return A_CUBIC * (((at - 5.0f) * at + 8.0f) * at - 4.0f);
    return 0.0f;
}

// K1: bicubic downscale tar -> s1, s2; build mT (k-major) rows; init best.
__global__ void prep_k(const float* __restrict__ tar, const float* __restrict__ inp,
                       float* __restrict__ s1, float* __restrict__ s2,
                       float* __restrict__ mT, unsigned long long* __restrict__ best) {
    int t = blockIdx.x * 256 + threadIdx.x;
    const int total1 = NB * NC * 72 * 72;
    const int total2 = NB * NC * 36 * 36;
    if (t < total1 + total2) {
        float* dst; int O; int idx;
        if (t < total1) { dst = s1; O = 72; idx = t; }
        else            { dst = s2; O = 36; idx = t - total1; }
        int x  = idx % O;
        int y  = (idx / O) % O;
        int bc = idx / (O * O);
        const float* src = tar + (size_t)bc * HH * HH;
        float scale = (float)(143.0 / (double)(O - 1));
        float fy = (float)y * scale;
        float iyf = floorf(fy); float fry = fy - iyf; int iy = (int)iyf;
        float fx = (float)x * scale;
        float ixf = floorf(fx); float frx = fx - ixf; int ix = (int)ixf;
        float wy[4], wx[4];
        #pragma unroll
        for (int d = 0; d < 4; ++d) {
            wy[d] = cubicw(fry - (float)(d - 1));
            wx[d] = cubicw(frx - (float)(d - 1));
        }
        float acc = 0.0f;
        #pragma unroll
        for (int dx = 0; dx < 4; ++dx) {
            int cx = min(max(ix - 1 + dx, 0), HH - 1);
            float inner = 0.0f;
            #pragma unroll
            for (int dy = 0; dy < 4; ++dy) {
                int cy = min(max(iy - 1 + dy, 0), HH - 1);
                inner += wy[dy] * src[cy * HH + cx];
            }
            acc += wx[dx] * inner;
        }
        dst[idx] = acc;
    } else {
        int u = t - (total1 + total2);
        if (u >= NTOT) return;
        int b = u / NPB, n = u % NPB;
        int hc = n / 48, wc = n % 48;
        const float* ib = inp + (size_t)b * NC * HH * HH;
        const float* tb = tar + (size_t)b * NC * HH * HH;
        #pragma unroll
        for (int c = 0; c < 3; ++c)
            #pragma unroll
            for (int dy = 0; dy < 3; ++dy)
                #pragma unroll
                for (int dx = 0; dx < 3; ++dx) {
                    int off = (c * HH + hc * 3 + dy) * HH + wc * 3 + dx;
                    int d   = (c * 3 + dy) * 3 + dx;
                    mT[d * NTOT + u] = ib[off] + tb[off];
                }
        mT[27 * NTOT + u] = -1.0f;
        best[u] = 0ULL;
    }
}

// K2: build gfT (k-major) [28][GTOT]; plane 27 = |g|^2; pad g>=GG zeroed.
__global__ void build_gf_k(const float* __restrict__ tar, const float* __restrict__ s1,
                           const float* __restrict__ s2, float* __restrict__ gfT) {
    int t = blockIdx.x * 256 + threadIdx.x;
    if (t >= GTOT) return;
    int b = t / GGP, g = t % GGP;
    if (g >= GG) {
        #pragma unroll
        for (int d = 0; d < 28; ++d) gfT[d * GTOT + t] = 0.0f;
        return;
    }
    int s = 0;
    #pragma unroll
    for (int k = 1; k < 15; ++k) if (g >= c_seg_start[k]) s = k;
    int p  = g - c_seg_start[s];
    int gw = c_seg_gw[s];
    int hc = p / gw, wc = p % gw;
    int oy = c_seg_oy[s], ox = c_seg_ox[s];
    int srci = c_seg_src[s];
    const float* img; int sz;
    if (srci == 0)      { img = tar; sz = 144; }
    else if (srci == 1) { img = s1;  sz = 72;  }
    else                { img = s2;  sz = 36;  }
    const float* base = img + (size_t)b * NC * sz * sz;
    int y0 = oy + hc * 3, x0 = ox + wc * 3;
    float acc = 0.0f;
    #pragma unroll
    for (int c = 0; c < 3; ++c)
        #pragma unroll
        for (int dy = 0; dy < 3; ++dy)
            #pragma unroll
            for (int dx = 0; dx < 3; ++dx) {
                float v = base[((size_t)c * sz + y0 + dy) * sz + x0 + dx];
                gfT[((c * 3 + dy) * 3 + dx) * GTOT + t] = v;
                acc = fmaf(v, v, acc);
            }
    gfT[27 * GTOT + t] = acc;
}

#define ROWM(am, i)                                                            \
    acc[i][0]=(am)*bp.x; acc[i][1]=(am)*bp.y; acc[i][2]=(am)*bp.z;             \
    acc[i][3]=(am)*bp.w; acc[i][4]=(am)*bq.x; acc[i][5]=(am)*bq.y;             \
    acc[i][6]=(am)*bq.z; acc[i][7]=(am)*bq.w;

#define ROWF(am, i)                                                            \
    acc[i][0]=fmaf((am),bp.x,acc[i][0]); acc[i][1]=fmaf((am),bp.y,acc[i][1]);  \
    acc[i][2]=fmaf((am),bp.z,acc[i][2]); acc[i][3]=fmaf((am),bp.w,acc[i][3]);  \
    acc[i][4]=fmaf((am),bq.x,acc[i][4]); acc[i][5]=fmaf((am),bq.y,acc[i][5]);  \
    acc[i][6]=fmaf((am),bq.z,acc[i][6]); acc[i][7]=fmaf((am),bq.w,acc[i][7]);

// K4: register-tiled GEMM + fused argmax. Block tile 128n x 128g, thread tile
// 8n x 8g (n split lo/hi: {4tx..4tx+3} u {64+4tx..67+4tx} -> stride-4 float4
// lane reads = 2-way bank aliasing = free). 4 ds_read_b128 feed 64 FMAs.
__global__ __launch_bounds__(256) void argmin_k(
        const float* __restrict__ gfT, const float* __restrict__ mT,
        unsigned long long* __restrict__ best) {
    __shared__ __align__(16) float S[28 * 128 * 2];  // 28 KB: Al [28][128], Bl [28][128]
    float* Al = S;
    float* Bl = S + 28 * 128;
    int tid = threadIdx.x;
    int tx = tid & 15, ty = tid >> 4;
    int nt = blockIdx.y;            // 0..35 (128 n each; 18 tiles per batch)
    int n0 = nt * 128;
    int b  = nt / 18;
    int s  = blockIdx.x;            // 0..NSPLIT-1
    int t0 = (s * NGT) / NSPLIT;
    int t1 = ((s + 1) * NGT) / NSPLIT;

    // stage A once: 28 k-planes x 32 float4
    for (int idx = tid; idx < 28 * 32; idx += 256) {
        int k = idx >> 5, x = idx & 31;
        *(float4*)&Al[k * 128 + x * 4] = *(const float4*)&mT[k * NTOT + n0 + x * 4];
    }

    float bv[8]; int bi[8];
    #pragma unroll
    for (int i = 0; i < 8; ++i) { bv[i] = -3.0e38f; bi[i] = 0; }

    const float* gb = gfT + b * GGP;
    for (int t = t0; t < t1; ++t) {
        __syncthreads();
        for (int idx = tid; idx < 28 * 32; idx += 256) {
            int k = idx >> 5, x = idx & 31;
            *(float4*)&Bl[k * 128 + x * 4] = *(const float4*)&gb[k * GTOT + t * 128 + x * 4];
        }
        __syncthreads();

        float acc[8][8];
        {
            float4 a0 = *(const float4*)&Al[tx * 4];
            float4 a1 = *(const float4*)&Al[64 + tx * 4];
            float4 bp = *(const float4*)&Bl[ty * 8];
            float4 bq = *(const float4*)&Bl[ty * 8 + 4];
            ROWM(a0.x, 0) ROWM(a0.y, 1) ROWM(a0.z, 2) ROWM(a0.w, 3)
            ROWM(a1.x, 4) ROWM(a1.y, 5) ROWM(a1.z, 6) ROWM(a1.w, 7)
        }
        #pragma unroll
        for (int k = 1; k < 28; ++k) {
            float4 a0 = *(const float4*)&Al[k * 128 + tx * 4];
            float4 a1 = *(const float4*)&Al[k * 128 + 64 + tx * 4];
            float4 bp = *(const float4*)&Bl[k * 128 + ty * 8];
            float4 bq = *(const float4*)&Bl[k * 128 + ty * 8 + 4];
            ROWF(a0.x, 0) ROWF(a0.y, 1) ROWF(a0.z, 2) ROWF(a0.w, 3)
            ROWF(a1.x, 4) ROWF(a1.y, 5) ROWF(a1.z, 6) ROWF(a1.w, 7)
        }

        int gg0 = t * 128 + ty * 8;
        #pragma unroll
        for (int j = 0; j < 8; ++j) {       // t,j ascending: strict > keeps first max
            #pragma unroll
            for (int i = 0; i < 8; ++i) {
                if (acc[i][j] > bv[i]) { bv[i] = acc[i][j]; bi[i] = gg0 + j; }
            }
        }
    }

    // reduce across ty (overlay Al/Bl space; all k-loop reads are done)
    __syncthreads();
    float* rv = S;                         // [128][17]
    int*   ri = (int*)(S + 128 * 17);      // [128][17]
    #pragma unroll
    for (int i = 0; i < 8; ++i) {
        int nl = (i < 4) ? (tx * 4 + i) : (64 + tx * 4 + i - 4);
        rv[nl * 17 + ty] = bv[i];
        ri[nl * 17 + ty] = bi[i];
    }
    __syncthreads();
    if (tid < 128) {
        float v = -3.0e38f; int idx = 0x7fffffff;
        #pragma unroll
        for (int y = 0; y < 16; ++y) {
            float vv = rv[tid * 17 + y]; int ii = ri[tid * 17 + y];
            if (vv > v || (vv == v && ii < idx)) { v = vv; idx = ii; }
        }
        unsigned u = __float_as_uint(v);
        u ^= (unsigned)(((int)u >> 31)) | 0x80000000u;
        atomicMax(&best[n0 + tid], ((unsigned long long)u << 32) | (unsigned)(~idx));
    }
}

// K5: decode best, gather sel (strided from gfT), fold, block-partial L1 sums
__global__ void finalize_k(const float* __restrict__ gfT,
                           const unsigned long long* __restrict__ best,
                           const float* __restrict__ inp,
                           float* __restrict__ out, float* __restrict__ lpart) {
    __shared__ float red[256];
    int t = blockIdx.x * 256 + threadIdx.x;
    float lsum = 0.0f;
    if (t < NTOT) {
        int b = t / NPB, n = t % NPB;
        unsigned long long pk = best[t];
        int bi = (int)(~(unsigned)(pk & 0xFFFFFFFFull));
        int hc = n / 48, wc = n % 48;
        const float* ib = inp + (size_t)b * NC * HH * HH;
        float* sel = out + 1 + (size_t)b * NC * HH * HH;
        #pragma unroll
        for (int c = 0; c < 3; ++c)
            #pragma unroll
            for (int dy = 0; dy < 3; ++dy)
                #pragma unroll
                for (int dx = 0; dx < 3; ++dx) {
                    int d = (c * 3 + dy) * 3 + dx;
                    float sv = gfT[(size_t)d * GTOT + b * GGP + bi];
                    int off = (c * HH + hc * 3 + dy) * HH + wc * 3 + dx;
                    sel[off] = sv;
                    lsum += fabsf(ib[off] - sv);
                }
    }
    red[threadIdx.x] = lsum;
    __syncthreads();
    for (int s = 128; s > 0; s >>= 1) {
        if (threadIdx.x < s) red[threadIdx.x] += red[threadIdx.x + s];
        __syncthreads();
    }
    if (threadIdx.x == 0) lpart[blockIdx.x] = red[0];
}

// K6: scalar loss mean
__global__ void sum_k(const float* __restrict__ lpart, float* __restrict__ out) {
    if (threadIdx.x == 0) {
        float s = 0.0f;
        for (int i = 0; i < 18; ++i) s += lpart[i];
        out[0] = s * (1.0f / 124416.0f);
    }
}

extern "C" void kernel_launch(void* const* d_in, const int* in_sizes, int n_in,
                              void* d_out, int out_size, void* d_ws, size_t ws_size,
                              hipStream_t stream) {
    const float* inp = (const float*)d_in[0];
    const float* tar = (const float*)d_in[1];
    float* out = (float*)d_out;
    float* ws  = (float*)d_ws;

    float* s1  = ws;                        // 31104
    float* s2  = s1 + 31104;                // 7776
    float* gfT = s2 + 7776;                 // 28*28928 = 809984
    float* mT  = gfT + 809984;              // 28*4608  = 129024
    unsigned long long* best = (unsigned long long*)(mT + 129024);  // 4608 u64
    float* lp  = (float*)(best + 4608);     // 18

    prep_k    <<<(43488 + 255) / 256, 256, 0, stream>>>(tar, inp, s1, s2, mT, best);
    build_gf_k<<<(GTOT + 255) / 256, 256, 0, stream>>>(tar, s1, s2, gfT);
    argmin_k  <<<dim3(NSPLIT, 36), 256, 0, stream>>>(gfT, mT, best);
    finalize_k<<<18, 256, 0, stream>>>(gfT, best, inp, out, lp);
    sum_k     <<<1, 64, 0, stream>>>(lp, out);
}